// Round 7
// baseline (477.939 us; speedup 1.0000x reference)
//
#include <hip/hip_runtime.h>
#include <hip/hip_fp16.h>
#include <cstdint>
#include <cstddef>

// Problem constants (fixed by the reference file)
#define DIM    384
#define HEADS  6
#define HD     64
#define NTOK   15768
#define NMID   1728
#define BATCH  2
#define ROWS   (BATCH*NTOK)   // 31536
#define MPAD   31616          // 247*128  (GEMM row-tile padding)
#define L1START 13824         // 8*NMID
#define L2START 15552         // 9*NMID
#define HID    96
#define VROWS  (ROWS + 8)     // +pad row for x==Dl spill (weight 0)
#define VSLAB  ((size_t)VROWS * 64)   // per-head slab in __half elements

typedef __attribute__((ext_vector_type(8))) short short8;   // 8 bf16 (4 VGPRs)
typedef __attribute__((ext_vector_type(4))) float floatx4;  // MFMA accumulator

__device__ __forceinline__ unsigned short f2bf(float x){
  unsigned u = __float_as_uint(x);
  unsigned r = (u + 0x7FFFu + ((u >> 16) & 1u)) >> 16;   // round-to-nearest-even
  return (unsigned short)r;
}

// packed f32x2 -> bf16x2 (RNE), single VOP3 instr
__device__ __forceinline__ unsigned cvt_pk_bf16(float lo, float hi){
  unsigned r;
  asm("v_cvt_pk_bf16_f32 %0, %1, %2" : "=v"(r) : "v"(lo), "v"(hi));
  return r;
}

// DPP helpers (VALU pipe -- replaces ds_swizzle/bpermute shuffles)
template<int C>
__device__ __forceinline__ int dpp_i(int v){
  return __builtin_amdgcn_mov_dpp(v, C, 0xF, 0xF, true);
}
template<int C>
__device__ __forceinline__ float dpp_f(float v){
  return __int_as_float(dpp_i<C>(__float_as_int(v)));
}
#define ROR8 0x128
#define ROR4 0x124
#define ROR2 0x122
#define ROR1 0x121

__device__ __forceinline__ __half2 h2_of(int v){ return *(__half2*)&v; }
__device__ __forceinline__ int i_of(__half2 v){ return *(int*)&v; }

// a[i] + a[i^32] in all lanes, VALU pipe (gfx950 v_permlane32_swap_b32)
__device__ __forceinline__ __half2 xor32_hadd(__half2 a){
  int x = i_of(a), y = x;
  asm volatile("v_permlane32_swap_b32 %0, %1" : "+v"(x), "+v"(y));
  return __hadd2(h2_of(x), h2_of(y));
}

__device__ __forceinline__ float wave_sum(float v){
  #pragma unroll
  for (int o = 32; o; o >>= 1) v += __shfl_xor(v, o, 64);
  return v;
}

// LayerNorm over 384 channels held as 6 regs/lane (c = j*64 + lane)
__device__ __forceinline__ void ln384(const float* x, float* y,
                                      const float* __restrict__ w,
                                      const float* __restrict__ b, int lane){
  float s = 0.f;
  #pragma unroll
  for (int j = 0; j < 6; j++) s += x[j];
  s = wave_sum(s);
  float m = s * (1.f/384.f);
  float v = 0.f;
  #pragma unroll
  for (int j = 0; j < 6; j++){ float d = x[j] - m; v += d*d; }
  v = wave_sum(v) * (1.f/384.f);
  float rs = rsqrtf(v + 1e-6f);
  #pragma unroll
  for (int j = 0; j < 6; j++){
    int c = j*64 + lane;
    y[j] = (x[j] - m) * rs * w[c] + b[c];
  }
}

// q = query (+feat on mid segment); qn=LN(q) f16; aq=LN(qn) bf16; af=LN(LN(q,fnorm)) bf16
__global__ void k_ln_front(const float* __restrict__ query, const float* __restrict__ feat,
                           const float* __restrict__ qw,  const float* __restrict__ qb,
                           const float* __restrict__ fw,  const float* __restrict__ fb,
                           const float* __restrict__ eqw, const float* __restrict__ eqb,
                           const float* __restrict__ efw, const float* __restrict__ efb,
                           __half* __restrict__ qn, unsigned short* __restrict__ aq,
                           unsigned short* __restrict__ af){
  int wid = blockIdx.x * (blockDim.x >> 6) + (threadIdx.x >> 6);
  if (wid >= ROWS) return;
  int lane = threadIdx.x & 63;
  int b = wid / NTOK, t = wid - b*NTOK;
  const float* qp = query + (size_t)wid * DIM;
  float x[6];
  #pragma unroll
  for (int j = 0; j < 6; j++) x[j] = qp[j*64 + lane];
  if (t >= L1START && t < L2START){
    const float* fp = feat + ((size_t)b*NMID + (t - L1START)) * DIM;
    #pragma unroll
    for (int j = 0; j < 6; j++) x[j] += fp[j*64 + lane];
  }
  float y[6], z[6];
  ln384(x, y, qw, qb, lane);                 // qn (residual for out-GEMM), f16
  {
    __half* o = qn + (size_t)wid * DIM;
    #pragma unroll
    for (int j = 0; j < 6; j++) o[j*64 + lane] = __float2half_rn(y[j]);
  }
  ln384(y, z, eqw, eqb, lane);               // aq = LN(qn)
  {
    unsigned short* o = aq + (size_t)wid * DIM;
    #pragma unroll
    for (int j = 0; j < 6; j++) o[j*64 + lane] = f2bf(z[j]);
  }
  ln384(x, y, fw, fb, lane);                 // fn
  ln384(y, z, efw, efb, lane);               // af = LN(fn)
  {
    unsigned short* o = af + (size_t)wid * DIM;
    #pragma unroll
    for (int j = 0; j < 6; j++) o[j*64 + lane] = f2bf(z[j]);
  }
}

// plain LN: out_bf16 = LN(in_f16, w, b)
__global__ void k_ln(const __half* __restrict__ in, const float* __restrict__ w,
                     const float* __restrict__ b, unsigned short* __restrict__ out){
  int wid = blockIdx.x * (blockDim.x >> 6) + (threadIdx.x >> 6);
  if (wid >= ROWS) return;
  int lane = threadIdx.x & 63;
  float x[6], y[6];
  const __half* p = in + (size_t)wid * DIM;
  #pragma unroll
  for (int j = 0; j < 6; j++) x[j] = __half2float(p[j*64 + lane]);
  ln384(x, y, w, b, lane);
  unsigned short* o = out + (size_t)wid * DIM;
  #pragma unroll
  for (int j = 0; j < 6; j++) o[j*64 + lane] = f2bf(y[j]);
}

// One-shot weight convert+transpose for all GEMMs + combined off/aw bias
// + zero-fill of the value-table pad rows (x==Dl spill target, weight 0).
__global__ void k_cvt_all(const float* __restrict__ val_w, const float* __restrict__ off_w,
                          const float* __restrict__ aw_w,  const float* __restrict__ out_w,
                          const float* __restrict__ fc1_w, const float* __restrict__ fc2_w,
                          const float* __restrict__ off_b, const float* __restrict__ aw_b,
                          unsigned short* __restrict__ wt_val, unsigned short* __restrict__ wt_offaw,
                          unsigned short* __restrict__ wt_out, unsigned short* __restrict__ wt_fc1,
                          unsigned short* __restrict__ wt_fc2, float* __restrict__ offaw_b,
                          unsigned short* __restrict__ vt_pad){
  int id = blockIdx.x * blockDim.x + threadIdx.x;
  if (id < 147456){                                   // val: K=384, Npad=384
    int n = id / 384, k = id - n*384;
    wt_val[id] = f2bf(val_w[(size_t)k*384 + n]);
  } else if (id < 294912){                            // off(216)+aw(72@256): K=384, Npad=384
    int i = id - 147456;
    int n = i / 384, k = i - n*384;
    float v = 0.f;
    if (n < 216) v = off_w[(size_t)k*216 + n];
    else if (n >= 256 && n < 328) v = aw_w[(size_t)k*72 + (n-256)];
    wt_offaw[i] = f2bf(v);
  } else if (id < 442368){                            // out: K=384, Npad=384
    int i = id - 294912;
    int n = i / 384, k = i - n*384;
    wt_out[i] = f2bf(out_w[(size_t)k*384 + n]);
  } else if (id < 491520){                            // fc1: K=384, N=96, Npad=128
    int i = id - 442368;
    int n = i / 384, k = i - n*384;
    wt_fc1[i] = f2bf((n < 96) ? fc1_w[(size_t)k*96 + n] : 0.f);
  } else if (id < 528384){                            // fc2: K=96, Npad=384
    int i = id - 491520;
    int n = i / 96, k = i - n*96;
    wt_fc2[i] = f2bf(fc2_w[(size_t)k*384 + n]);
  } else if (id < 528768){                            // combined off/aw bias [384]
    int n = id - 528384;
    float v = 0.f;
    if (n < 216) v = off_b[n];
    else if (n >= 256 && n < 328) v = aw_b[n-256];
    offaw_b[n] = v;
  } else if (id < 531840){                            // value pad rows: 6 heads x 8 rows x 64 ch
    int i = id - 528768;
    int hh = i >> 9, rem = i & 511;
    vt_pad[(size_t)hh * VSLAB + (size_t)ROWS * 64 + rem] = 0;
  }
}

// Shared GEMM body: 128x128 tile, BK=32, 256 threads, 2-phase dbuf global_load_lds.
#define GEMM_BODY(A, Wt, K)                                                        \
  __shared__ __align__(16) unsigned short As[2*128*32];                            \
  __shared__ __align__(16) unsigned short Bs[2*128*32];                            \
  int tid = threadIdx.x;                                                           \
  int w = tid >> 6, lane = tid & 63;                                               \
  int m0 = blockIdx.y * 128, n0 = blockIdx.x * 128;                                \
  int m_off = (w & 1) * 64, n_off = (w >> 1) * 64;                                 \
  floatx4 acc[4][4] = {};                                                          \
  int sr = lane >> 2;                                                              \
  int sc = (lane & 3) * 8;                                                         \
  int lrow = lane & 15;                                                            \
  int kq = (lane >> 4) * 8;                                                        \
  GSTAGE(0, 0)                                                                     \
  __syncthreads();                                                                 \
  int cur = 0;                                                                     \
  for (int k0 = 0; k0 < (K); k0 += 32){                                            \
    if (k0 + 32 < (K)){ GSTAGE(cur ^ 1, k0 + 32) }                                 \
    const unsigned short* Ab = As + cur*4096;                                      \
    const unsigned short* Bb = Bs + cur*4096;                                      \
    short8 afr[4], bfr[4];                                                         \
    _Pragma("unroll")                                                              \
    for (int i = 0; i < 4; i++)                                                    \
      afr[i] = *(const short8*)(Ab + (m_off + i*16 + lrow)*32 + kq);               \
    _Pragma("unroll")                                                              \
    for (int j = 0; j < 4; j++)                                                    \
      bfr[j] = *(const short8*)(Bb + (n_off + j*16 + lrow)*32 + kq);               \
    _Pragma("unroll")                                                              \
    for (int i = 0; i < 4; i++)                                                    \
      _Pragma("unroll")                                                            \
      for (int j = 0; j < 4; j++)                                                  \
        acc[i][j] = __builtin_amdgcn_mfma_f32_16x16x32_bf16(afr[i], bfr[j],        \
                                                            acc[i][j], 0, 0, 0);  \
    __syncthreads();                                                               \
    cur ^= 1;                                                                      \
  }

#define GSTAGE(BUF, K0) { \
    _Pragma("unroll") \
    for (int s2 = 0; s2 < 2; s2++){ \
      int c = w * 2 + s2; \
      const unsigned short* ga = A  + (size_t)(m0 + c*16 + sr) * K + (K0) + sc; \
      __builtin_amdgcn_global_load_lds( \
          (const __attribute__((address_space(1))) void*)ga, \
          (__attribute__((address_space(3))) void*)(As + (BUF)*4096 + c*512), 16, 0, 0); \
      const unsigned short* gb = Wt + (size_t)(n0 + c*16 + sr) * K + (K0) + sc; \
      __builtin_amdgcn_global_load_lds( \
          (const __attribute__((address_space(1))) void*)gb, \
          (__attribute__((address_space(3))) void*)(Bs + (BUF)*4096 + c*512), 16, 0, 0); \
    } }

// bf16 MFMA GEMM: C[M,N] = A[Mpad,K]bf16 @ Wt[Npad,K]bf16^T + bias (+R f16).
// OUTMODE: 0 = f32 row-major; 3 = f16 row-major
template<int OUTMODE>
__global__ __launch_bounds__(256) void k_gemm(
    const unsigned short* __restrict__ A,
    const unsigned short* __restrict__ Wt,
    const float* __restrict__ bias,
    const __half* __restrict__ R,
    void* __restrict__ Cv,
    int M, int N, int K){
  GEMM_BODY(A, Wt, K)
  int cn = n0 + n_off + lrow;
  int rbase = m0 + m_off + (lane >> 4) * 4;
  #pragma unroll
  for (int j = 0; j < 4; j++){
    int n = cn + j*16;
    if (n >= N) continue;
    float bj = bias[n];
    #pragma unroll
    for (int i = 0; i < 4; i++){
      int mb = rbase + i*16;
      #pragma unroll
      for (int r = 0; r < 4; r++){
        int m = mb + r;
        if (m < M){
          float v = acc[i][j][r] + bj;
          if (R) v += __half2float(R[(size_t)m * N + n]);
          if (OUTMODE == 0) ((float*)Cv)[(size_t)m * N + n] = v;
          else              ((__half*)Cv)[(size_t)m * N + n] = __float2half_rn(v);
        }
      }
    }
  }
}

// Merged val+offaw GEMM (independent, same shape): grid.z selects the problem.
// z=0: value = af @ val_w (f16 value-layout [head][row][64]).
// z=1: offaw = aq @ [off|aw]_w (f32 row-major -- msdeform is request-bound and
//      wants dword-aligned descriptor reads; f16 offaw regressed it 7us in v11).
__global__ __launch_bounds__(256) void k_gemm_pair(
    const unsigned short* __restrict__ A0, const unsigned short* __restrict__ W0,
    const float* __restrict__ b0, __half* __restrict__ C0,
    const unsigned short* __restrict__ A1, const unsigned short* __restrict__ W1,
    const float* __restrict__ b1, float* __restrict__ C1,
    int M, int N, int K){
  int z = blockIdx.z;
  const unsigned short* A  = z ? A1 : A0;
  const unsigned short* Wt = z ? W1 : W0;
  const float* bias = z ? b1 : b0;
  GEMM_BODY(A, Wt, K)
  int cn = n0 + n_off + lrow;
  int rbase = m0 + m_off + (lane >> 4) * 4;
  #pragma unroll
  for (int j = 0; j < 4; j++){
    int n = cn + j*16;
    if (n >= N) continue;
    float bj = bias[n];
    #pragma unroll
    for (int i = 0; i < 4; i++){
      int mb = rbase + i*16;
      #pragma unroll
      for (int r = 0; r < 4; r++){
        int m = mb + r;
        if (m < M){
          float v = acc[i][j][r] + bj;
          if (z == 0)  // f16 value layout: [head = n>>6][row = m][ch = n&63]
            C0[(size_t)(n >> 6) * VSLAB + (size_t)m * 64 + (n & 63)] = __float2half_rn(v);
          else
            C1[(size_t)m * N + n] = v;
        }
      }
    }
  }
}

// Multi-scale deformable sampling v12 == v8 structure (best measured config:
// 1-wave blocks, chunked XCD swizzle, f32 offaw, DPP softmax, LDS dsc table,
// permlane reduce; ~73% of the L2-gather roofline). SPLIT INTO 2 LAUNCHES of
// 3 heads each (base = 0 / ROWS*3): perf-neutral, but drops the rocprof top-5
// threshold to ~46us so any hidden heavyweight kernel must surface -- the
// non-msdeform block has been invariant at ~379us across 6 rounds while
// roofline models say ~100-180us; this is the discriminating experiment.
__global__ __launch_bounds__(64, 4) void k_msdeform(const __half* __restrict__ vt,
                                                    const float* __restrict__ offaw,
                                                    unsigned short* __restrict__ msout,
                                                    int base){
  __shared__ __align__(16) int2 dsc[48];   // [grp][j] = {row, wgt} pairs
  int bid = blockIdx.x;
  // chunked XCD swizzle within this launch's half (94608 = 8*11826 blocks)
  int seq = base + (bid & 7) * ((ROWS*HEADS/2)/8) + (bid >> 3);
  int head = seq / ROWS;
  int r = seq - head * ROWS;
  int lane = threadIdx.x & 63;
  int b = (r >= NTOK) ? 1 : 0;
  int t = r - b * NTOK;

  // wave-uniform level branch; compile-time divisors -> magic-mul (scalar)
  float refd, refy, refx;
  if (t < L1START){
    int i = t;
    int dd = i / 576; int rem = i - dd*576; int yy = rem / 24; int xx = rem - yy*24;
    refd = (dd + 0.5f) * (1.f/24.f); refy = (yy + 0.5f) * (1.f/24.f); refx = (xx + 0.5f) * (1.f/24.f);
  } else if (t < L2START){
    int i = t - L1START;
    int dd = i / 144; int rem = i - dd*144; int yy = rem / 12; int xx = rem - yy*12;
    refd = (dd + 0.5f) * (1.f/12.f); refy = (yy + 0.5f) * (1.f/12.f); refx = (xx + 0.5f) * (1.f/12.f);
  } else {
    int i = t - L2START;
    int dd = i / 36; int rem = i - dd*36; int yy = rem / 6; int xx = rem - yy*6;
    refd = (dd + 0.5f) * (1.f/6.f); refy = (yy + 0.5f) * (1.f/6.f); refx = (xx + 0.5f) * (1.f/6.f);
  }

  int s   = lane & 15;     // point index (0..11 active) within group
  int grp = lane >> 4;     // (z,y) corner pair p == consumer group

  // softmax over the 12 (level,point) logits, replicated per 16-lane row
  float logit = (s < 12) ? offaw[(size_t)r * 384 + 256 + head * 12 + s] : -1e30f;
  float mx = logit;
  mx = fmaxf(mx, dpp_f<ROR8>(mx));
  mx = fmaxf(mx, dpp_f<ROR4>(mx));
  mx = fmaxf(mx, dpp_f<ROR2>(mx));
  mx = fmaxf(mx, dpp_f<ROR1>(mx));
  float e = (s < 12) ? __expf(logit - mx) : 0.f;
  float sum = e;
  sum += dpp_f<ROR8>(sum);
  sum += dpp_f<ROR4>(sum);
  sum += dpp_f<ROR2>(sum);
  sum += dpp_f<ROR1>(sum);
  float aww = e / sum;     // lane p*16+j holds softmax weight of point j

  // per-lane pair descriptor: lane p*16+j -> point j, (cz,cy) pair p
  if (s < 12){
    int j = s;
    int l = j >> 2;
    int Dl  = (l == 0) ? 24 : ((l == 1) ? 12 : 6);
    int lst = (l == 0) ? 0  : ((l == 1) ? L1START : L2START);
    const float* op = offaw + (size_t)r * 384 + head * 36 + j * 3;
    float od = op[0], ox = op[1], oy = op[2];
    float fDl = (float)Dl;
    float pd = refd * fDl + od - 0.5f;
    float px = refx * fDl + ox - 0.5f;
    float py = refy * fDl + oy - 0.5f;
    float fld = floorf(pd), flx = floorf(px), fly = floorf(py);
    float fd = pd - fld, fx = px - flx, fy = py - fly;
    int d0 = (int)fld, x0 = (int)flx, y0 = (int)fly;
    int cz = grp >> 1, cy = grp & 1;
    int di = d0 + cz, yi = y0 + cy;
    bool vzy = (di >= 0) & (di < Dl) & (yi >= 0) & (yi < Dl);
    float wz = cz ? fd : 1.f - fd;
    float wy = cy ? fy : 1.f - fy;
    float wp = vzy ? (wz * aww) * wy : 0.f;
    int rs = min(max(x0, 0), Dl - 1);
    float wlo_x = (rs == x0) ? (1.f - fx) : ((rs == x0 + 1) ? fx : 0.f);
    float whi_x = ((rs == x0) && (x0 + 1 < Dl)) ? fx : 0.f;
    int dc = min(max(di, 0), Dl - 1);
    int yc = min(max(yi, 0), Dl - 1);
    int rowk = (b * NTOK + lst) + (dc * Dl + yc) * Dl + rs;    // < 32768
    __half2 wh = __floats2half2_rn(wp * wlo_x, wp * whi_x);
    dsc[grp * 12 + s] = make_int2(rowk, *(int*)&wh);
  }
  // intra-wave LDS dependency: compiler inserts lgkmcnt wait (single wave/block)
  const uint4* dq = (const uint4*)dsc;
  uint4 dp0 = dq[grp*6+0], dp1 = dq[grp*6+1], dp2 = dq[grp*6+2];
  uint4 dp3 = dq[grp*6+3], dp4 = dq[grp*6+4], dp5 = dq[grp*6+5];

  const char* vbase = (const char*)(vt + (size_t)head * VSLAB);   // uniform SGPR base
  unsigned laneoff = (unsigned)(lane & 15) << 4;  // 16 lanes x 16B = rows rs & rs+1
  // lanes s<8 read row rs (x-lo weight), s>=8 row rs+1 (x-hi)
  unsigned selperm = (lane & 8) ? 0x03020302u : 0x01000100u;

  int rw[12] = {(int)dp0.x,(int)dp0.z,(int)dp1.x,(int)dp1.z,(int)dp2.x,(int)dp2.z,
                (int)dp3.x,(int)dp3.z,(int)dp4.x,(int)dp4.z,(int)dp5.x,(int)dp5.z};
  unsigned wg[12] = {dp0.y,dp0.w,dp1.y,dp1.w,dp2.y,dp2.w,
                     dp3.y,dp3.w,dp4.y,dp4.w,dp5.y,dp5.w};

  uint4 vd[12];
  #pragma unroll
  for (int j = 0; j < 12; j++)
    vd[j] = *(const uint4*)(vbase + ((((unsigned)rw[j]) << 7) + laneoff));
  unsigned wsel[12];
  #pragma unroll
  for (int j = 0; j < 12; j++)
    wsel[j] = __builtin_amdgcn_perm(wg[j], wg[j], selperm);

  __half2 hz; *(int*)&hz = 0;
  __half2 a0 = hz, a1 = hz, a2 = hz, a3 = hz;
  #pragma unroll
  for (int j = 0; j < 12; j++){
    __half2 wh = *(__half2*)&wsel[j];
    uint4 v = vd[j];
    a0 = __hfma2(wh, *(__half2*)&v.x, a0);
    a1 = __hfma2(wh, *(__half2*)&v.y, a1);
    a2 = __hfma2(wh, *(__half2*)&v.z, a2);
    a3 = __hfma2(wh, *(__half2*)&v.w, a3);
  }

  // reduce: xor-8 (x-lo + x-hi) via DPP ror8; xor-16 via shfl; xor-32 via
  // permlane32_swap. Packed f16 adds throughout.
  a0 = __hadd2(a0, h2_of(dpp_i<ROR8>(i_of(a0))));
  a1 = __hadd2(a1, h2_of(dpp_i<ROR8>(i_of(a1))));
  a2 = __hadd2(a2, h2_of(dpp_i<ROR8>(i_of(a2))));
  a3 = __hadd2(a3, h2_of(dpp_i<ROR8>(i_of(a3))));
  {
    int t0 = __shfl_xor(i_of(a0), 16, 64); a0 = __hadd2(a0, h2_of(t0));
    int t1 = __shfl_xor(i_of(a1), 16, 64); a1 = __hadd2(a1, h2_of(t1));
    int t2 = __shfl_xor(i_of(a2), 16, 64); a2 = __hadd2(a2, h2_of(t2));
    int t3 = __shfl_xor(i_of(a3), 16, 64); a3 = __hadd2(a3, h2_of(t3));
  }
  a0 = xor32_hadd(a0);
  a1 = xor32_hadd(a1);
  a2 = xor32_hadd(a2);
  a3 = xor32_hadd(a3);

  // lane L<8 holds channels L*8 .. L*8+7 -> one 16B bf16 store per lane
  if (lane < 8){
    float2 f0 = __half22float2(a0), f1 = __half22float2(a1);
    float2 f2 = __half22float2(a2), f3 = __half22float2(a3);
    uint4 pk;
    pk.x = cvt_pk_bf16(f0.x, f0.y);
    pk.y = cvt_pk_bf16(f1.x, f1.y);
    pk.z = cvt_pk_bf16(f2.x, f2.y);
    pk.w = cvt_pk_bf16(f3.x, f3.y);
    *(uint4*)(msout + (size_t)r * DIM + head * 64 + lane * 8) = pk;
  }
}

// depthwise 3x3x3 SAME conv per level segment + exact GELU; bf16 output.
// h input in f16 (half read traffic through L1/L2 for the 27-tap re-reads).
__global__ void k_dwconv_gelu(const __half* __restrict__ h, const float* __restrict__ dww,
                              const float* __restrict__ dwb, unsigned short* __restrict__ h2){
  int gid = blockIdx.x * blockDim.x + threadIdx.x;
  if (gid >= ROWS * 24) return;
  int c4 = gid % 24;
  int r = gid / 24;
  int c = c4 * 4;
  int b = (r >= NTOK) ? 1 : 0;
  int t = r - b * NTOK;
  int base, DL, i;
  if (t < L1START){ base = 0; DL = 24; i = t; }
  else if (t < L2START){ base = L1START; DL = 12; i = t - L1START; }
  else { base = L2START; DL = 6; i = t - L2START; }
  int dd, yy, xx;
  if (DL == 24){ dd = i / 576; int rem = i - dd*576; yy = rem / 24; xx = rem - yy*24; }
  else if (DL == 12){ dd = i / 144; int rem = i - dd*144; yy = rem / 12; xx = rem - yy*12; }
  else { dd = i / 36; int rem = i - dd*36; yy = rem / 6; xx = rem - yy*6; }
  float4 acc = {0.f, 0.f, 0.f, 0.f};
  #pragma unroll
  for (int kz = 0; kz < 3; kz++){
    int nd = dd + kz - 1; if (nd < 0 || nd >= DL) continue;
    #pragma unroll
    for (int ky = 0; ky < 3; ky++){
      int ny = yy + ky - 1; if (ny < 0 || ny >= DL) continue;
      #pragma unroll
      for (int kx = 0; kx < 3; kx++){
        int nx = xx + kx - 1; if (nx < 0 || nx >= DL) continue;
        int nt = base + (nd * DL + ny) * DL + nx;
        uint2 raw = *(const uint2*)(h + ((size_t)(b*NTOK + nt)) * HID + c);
        float2 h01 = __half22float2(h2_of((int)raw.x));
        float2 h23 = __half22float2(h2_of((int)raw.y));
        float4 wv = *(const float4*)(dww + (size_t)((kz*3 + ky)*3 + kx) * HID + c);
        acc.x += h01.x * wv.x; acc.y += h01.y * wv.y;
        acc.z += h23.x * wv.z; acc.w += h23.y * wv.w;
      }
    }
  }
  float4 bv = *(const float4*)(dwb + c);
  acc.x += bv.x; acc.y += bv.y; acc.z += bv.z; acc.w += bv.w;
  const float k = 0.70710678118654752440f;
  float g0 = 0.5f * acc.x * (1.f + erff(acc.x * k));
  float g1 = 0.5f * acc.y * (1.f + erff(acc.y * k));
  float g2 = 0.5f * acc.z * (1.f + erff(acc.z * k));
  float g3 = 0.5f * acc.w * (1.f + erff(acc.w * k));
  uint2 pk;
  pk.x = ((unsigned)f2bf(g1) << 16) | (unsigned)f2bf(g0);
  pk.y = ((unsigned)f2bf(g3) << 16) | (unsigned)f2bf(g2);
  *(uint2*)(h2 + (size_t)r * HID + c) = pk;
}

extern "C" void kernel_launch(void* const* d_in, const int* in_sizes, int n_in,
                              void* d_out, int out_size, void* d_ws, size_t ws_size,
                              hipStream_t stream){
  const float* query = (const float*)d_in[0];
  const float* feat  = (const float*)d_in[2];
  const float* qnw = (const float*)d_in[8],  *qnb = (const float*)d_in[9];
  const float* fnw = (const float*)d_in[10], *fnb = (const float*)d_in[11];
  const float* eqw = (const float*)d_in[12], *eqb = (const float*)d_in[13];
  const float* efw = (const float*)d_in[14], *efb = (const float*)d_in[15];
  const float* ffw = (const float*)d_in[16], *ffb = (const float*)d_in[17];
  const float* off_w = (const float*)d_in[18], *off_b = (const float*)d_in[19];
  const float* aw_w  = (const float*)d_in[20], *aw_b  = (const float*)d_in[21];
  const float* val_w = (const float*)d_in[22], *val_b = (const float*)d_in[23];
  const float* out_w = (const float*)d_in[24], *out_b = (const float*)d_in[25];
  const float* fc1_w = (const float*)d_in[26], *fc1_b = (const float*)d_in[27];
  const float* dw_w  = (const float*)d_in[28], *dw_b  = (const float*)d_in[29];
  const float* fc2_w = (const float*)d_in[30], *fc2_b = (const float*)d_in[31];
  float* out = (float*)d_out;

  // workspace layout (lifetime-disjoint aliasing)
  char* p = (char*)d_ws;
  __half* qn            = (__half*)p;         p += (size_t)ROWS*384*2;  // qn f16; later h2
  unsigned short* aq    = (unsigned short*)p; p += (size_t)MPAD*384*2;  // aq -> t
  unsigned short* af    = (unsigned short*)p; p += (size_t)MPAD*384*2;  // af -> msout
  __half* value_t       = (__half*)p;         p += (size_t)HEADS*VSLAB*2; // value; later h
  float* offaw          = (float*)p;          p += (size_t)ROWS*384*4;  // off+aw f32; later y1
  unsigned short* wt_val   = (unsigned short*)p; p += (size_t)384*384*2;
  unsigned short* wt_offaw = (unsigned short*)p; p += (size_t)384*384*2;
  unsigned short* wt_out   = (unsigned short*)p; p += (size_t)384*384*2;
  unsigned short* wt_fc1   = (unsigned short*)p; p += (size_t)128*384*2;
  unsigned short* wt_fc2   = (unsigned short*)p; p += (size_t)384*96*2;
  float* offaw_b           = (float*)p;          p += (size_t)384*4;
  // aliases (lifetime-disjoint)
  unsigned short* t_buf  = aq;                    // MPAD*384 bf16
  unsigned short* msout  = af;                    // MPAD*384 bf16
  __half* y1             = (__half*)offaw;        // ROWS*384 f16 (offaw dead post-msdeform)
  __half* h_buf          = value_t;               // ROWS*96 f16 (value dead post-msdeform)
  unsigned short* h2_buf = (unsigned short*)qn;   // MPAD*96 bf16 (qn dead post-out-GEMM)

  k_cvt_all<<<(531840 + 255)/256, 256, 0, stream>>>(val_w, off_w, aw_w, out_w, fc1_w, fc2_w,
                                                    off_b, aw_b,
                                                    wt_val, wt_offaw, wt_out, wt_fc1, wt_fc2,
                                                    offaw_b, (unsigned short*)value_t);

  int lnBlocks = ROWS / 4;
  k_ln_front<<<lnBlocks, 256, 0, stream>>>(query, feat, qnw, qnb, fnw, fnb,
                                           eqw, eqb, efw, efb, qn, aq, af);

  dim3 gN384(3, MPAD/128), gN128(1, MPAD/128), gPair(3, MPAD/128, 2);

  // value (f16 [head][row][64]) and offaw (f32 row-major) in ONE launch
  k_gemm_pair<<<gPair, 256, 0, stream>>>(af, wt_val, val_b, value_t,
                                         aq, wt_offaw, offaw_b, offaw,
                                         ROWS, 384, 384);
  // deformable sampling -> msout (bf16; af dead). TWO half-launches (3 heads
  // each): perf-neutral diagnostic -- drops top-5 threshold to ~46us.
  k_msdeform<<<(ROWS*HEADS)/2, 64, 0, stream>>>(value_t, offaw, msout, 0);
  k_msdeform<<<(ROWS*HEADS)/2, 64, 0, stream>>>(value_t, offaw, msout, (ROWS*HEADS)/2);
  // y1(f16) = msout @ out_w + out_b + qn(f16)   (offaw dead)
  k_gemm<3><<<gN384, 256, 0, stream>>>(msout, wt_out, out_b, qn, y1, ROWS, 384, 384);
  // t = LN(y1, ffn_norm)  (aq dead)
  k_ln<<<lnBlocks, 256, 0, stream>>>(y1, ffw, ffb, t_buf);
  // h(f16) = t @ fc1_w + fc1_b   (value dead)
  k_gemm<3><<<gN128, 256, 0, stream>>>(t_buf, wt_fc1, fc1_b, nullptr, h_buf, ROWS, 96, 384);
  // h2 = gelu(dwconv(h))    (qn dead)
  k_dwconv_gelu<<<(ROWS * 24 + 255)/256, 256, 0, stream>>>(h_buf, dw_w, dw_b, h2_buf);
  // out(f32) = h2 @ fc2_w + fc2_b + y1(f16)
  k_gemm<0><<<gN384, 256, 0, stream>>>(h2_buf, wt_fc2, fc2_b, y1, out, ROWS, 384, 96);
}

// Round 9
// 441.122 us; speedup vs baseline: 1.0835x; 1.0835x over previous
//
#include <hip/hip_runtime.h>
#include <hip/hip_fp16.h>
#include <cstdint>
#include <cstddef>

// Problem constants (fixed by the reference file)
#define DIM    384
#define HEADS  6
#define HD     64
#define NTOK   15768
#define NMID   1728
#define BATCH  2
#define ROWS   (BATCH*NTOK)   // 31536
#define MPAD   31616          // 247*128  (GEMM row-tile padding)
#define L1START 13824         // 8*NMID
#define L2START 15552         // 9*NMID
#define HID    96
#define VROWS  (ROWS + 8)     // +pad row for x==Dl spill (weight 0)
#define VSLAB  ((size_t)VROWS * 64)   // per-head slab in __half elements

typedef __attribute__((ext_vector_type(8))) short short8;   // 8 bf16 (4 VGPRs)
typedef __attribute__((ext_vector_type(4))) float floatx4;  // MFMA accumulator

__device__ __forceinline__ unsigned short f2bf(float x){
  unsigned u = __float_as_uint(x);
  unsigned r = (u + 0x7FFFu + ((u >> 16) & 1u)) >> 16;   // round-to-nearest-even
  return (unsigned short)r;
}

// packed f32x2 -> bf16x2 (RNE), single VOP3 instr
__device__ __forceinline__ unsigned cvt_pk_bf16(float lo, float hi){
  unsigned r;
  asm("v_cvt_pk_bf16_f32 %0, %1, %2" : "=v"(r) : "v"(lo), "v"(hi));
  return r;
}

// DPP helpers (VALU pipe)
template<int C>
__device__ __forceinline__ int dpp_i(int v){
  return __builtin_amdgcn_mov_dpp(v, C, 0xF, 0xF, true);
}
template<int C>
__device__ __forceinline__ float dpp_f(float v){
  return __int_as_float(dpp_i<C>(__float_as_int(v)));
}
#define ROR8 0x128
#define ROR4 0x124
#define ROR2 0x122
#define ROR1 0x121

__device__ __forceinline__ __half2 h2_of(int v){ return *(__half2*)&v; }
__device__ __forceinline__ int i_of(__half2 v){ return *(int*)&v; }

// a[i] + a[i^32] in all lanes, VALU pipe (gfx950 v_permlane32_swap_b32)
__device__ __forceinline__ __half2 xor32_hadd(__half2 a){
  int x = i_of(a), y = x;
  asm volatile("v_permlane32_swap_b32 %0, %1" : "+v"(x), "+v"(y));
  return __hadd2(h2_of(x), h2_of(y));
}

__device__ __forceinline__ float wave_sum(float v){
  #pragma unroll
  for (int o = 32; o; o >>= 1) v += __shfl_xor(v, o, 64);
  return v;
}

// LayerNorm over 384 channels held as 6 regs/lane (c = j*64 + lane)
__device__ __forceinline__ void ln384(const float* x, float* y,
                                      const float* __restrict__ w,
                                      const float* __restrict__ b, int lane){
  float s = 0.f;
  #pragma unroll
  for (int j = 0; j < 6; j++) s += x[j];
  s = wave_sum(s);
  float m = s * (1.f/384.f);
  float v = 0.f;
  #pragma unroll
  for (int j = 0; j < 6; j++){ float d = x[j] - m; v += d*d; }
  v = wave_sum(v) * (1.f/384.f);
  float rs = rsqrtf(v + 1e-6f);
  #pragma unroll
  for (int j = 0; j < 6; j++){
    int c = j*64 + lane;
    y[j] = (x[j] - m) * rs * w[c] + b[c];
  }
}

// q = query (+feat on mid segment); qn=LN(q) f16; aq=LN(qn) bf16; af=LN(LN(q,fnorm)) bf16
__global__ void k_ln_front(const float* __restrict__ query, const float* __restrict__ feat,
                           const float* __restrict__ qw,  const float* __restrict__ qb,
                           const float* __restrict__ fw,  const float* __restrict__ fb,
                           const float* __restrict__ eqw, const float* __restrict__ eqb,
                           const float* __restrict__ efw, const float* __restrict__ efb,
                           __half* __restrict__ qn, unsigned short* __restrict__ aq,
                           unsigned short* __restrict__ af){
  int wid = blockIdx.x * (blockDim.x >> 6) + (threadIdx.x >> 6);
  if (wid >= ROWS) return;
  int lane = threadIdx.x & 63;
  int b = wid / NTOK, t = wid - b*NTOK;
  const float* qp = query + (size_t)wid * DIM;
  float x[6];
  #pragma unroll
  for (int j = 0; j < 6; j++) x[j] = qp[j*64 + lane];
  if (t >= L1START && t < L2START){
    const float* fp = feat + ((size_t)b*NMID + (t - L1START)) * DIM;
    #pragma unroll
    for (int j = 0; j < 6; j++) x[j] += fp[j*64 + lane];
  }
  float y[6], z[6];
  ln384(x, y, qw, qb, lane);                 // qn (residual for out-GEMM), f16
  {
    __half* o = qn + (size_t)wid * DIM;
    #pragma unroll
    for (int j = 0; j < 6; j++) o[j*64 + lane] = __float2half_rn(y[j]);
  }
  ln384(y, z, eqw, eqb, lane);               // aq = LN(qn)
  {
    unsigned short* o = aq + (size_t)wid * DIM;
    #pragma unroll
    for (int j = 0; j < 6; j++) o[j*64 + lane] = f2bf(z[j]);
  }
  ln384(x, y, fw, fb, lane);                 // fn
  ln384(y, z, efw, efb, lane);               // af = LN(fn)
  {
    unsigned short* o = af + (size_t)wid * DIM;
    #pragma unroll
    for (int j = 0; j < 6; j++) o[j*64 + lane] = f2bf(z[j]);
  }
}

// plain LN: out_bf16 = LN(in_f16, w, b)
__global__ void k_ln(const __half* __restrict__ in, const float* __restrict__ w,
                     const float* __restrict__ b, unsigned short* __restrict__ out){
  int wid = blockIdx.x * (blockDim.x >> 6) + (threadIdx.x >> 6);
  if (wid >= ROWS) return;
  int lane = threadIdx.x & 63;
  float x[6], y[6];
  const __half* p = in + (size_t)wid * DIM;
  #pragma unroll
  for (int j = 0; j < 6; j++) x[j] = __half2float(p[j*64 + lane]);
  ln384(x, y, w, b, lane);
  unsigned short* o = out + (size_t)wid * DIM;
  #pragma unroll
  for (int j = 0; j < 6; j++) o[j*64 + lane] = f2bf(y[j]);
}

// One-shot weight convert+transpose for all GEMMs + combined off/aw bias
// + zero-fill of the value-table pad rows (x==Dl spill target, weight 0).
__global__ void k_cvt_all(const float* __restrict__ val_w, const float* __restrict__ off_w,
                          const float* __restrict__ aw_w,  const float* __restrict__ out_w,
                          const float* __restrict__ fc1_w, const float* __restrict__ fc2_w,
                          const float* __restrict__ off_b, const float* __restrict__ aw_b,
                          unsigned short* __restrict__ wt_val, unsigned short* __restrict__ wt_offaw,
                          unsigned short* __restrict__ wt_out, unsigned short* __restrict__ wt_fc1,
                          unsigned short* __restrict__ wt_fc2, float* __restrict__ offaw_b,
                          unsigned short* __restrict__ vt_pad){
  int id = blockIdx.x * blockDim.x + threadIdx.x;
  if (id < 147456){                                   // val: K=384, Npad=384
    int n = id / 384, k = id - n*384;
    wt_val[id] = f2bf(val_w[(size_t)k*384 + n]);
  } else if (id < 294912){                            // off(216)+aw(72@256): K=384, Npad=384
    int i = id - 147456;
    int n = i / 384, k = i - n*384;
    float v = 0.f;
    if (n < 216) v = off_w[(size_t)k*216 + n];
    else if (n >= 256 && n < 328) v = aw_w[(size_t)k*72 + (n-256)];
    wt_offaw[i] = f2bf(v);
  } else if (id < 442368){                            // out: K=384, Npad=384
    int i = id - 294912;
    int n = i / 384, k = i - n*384;
    wt_out[i] = f2bf(out_w[(size_t)k*384 + n]);
  } else if (id < 491520){                            // fc1: K=384, N=96, Npad=128
    int i = id - 442368;
    int n = i / 384, k = i - n*384;
    wt_fc1[i] = f2bf((n < 96) ? fc1_w[(size_t)k*96 + n] : 0.f);
  } else if (id < 528384){                            // fc2: K=96, Npad=384
    int i = id - 491520;
    int n = i / 96, k = i - n*96;
    wt_fc2[i] = f2bf(fc2_w[(size_t)k*384 + n]);
  } else if (id < 528768){                            // combined off/aw bias [384]
    int n = id - 528384;
    float v = 0.f;
    if (n < 216) v = off_b[n];
    else if (n >= 256 && n < 328) v = aw_b[n-256];
    offaw_b[n] = v;
  } else if (id < 531840){                            // value pad rows: 6 heads x 8 rows x 64 ch
    int i = id - 528768;
    int hh = i >> 9, rem = i & 511;
    vt_pad[(size_t)hh * VSLAB + (size_t)ROWS * 64 + rem] = 0;
  }
}

// ---- shared GEMM pieces: 128x128 tile, BK=32, 256 threads, 2-phase dbuf ----
#define GEMM_DECL(Kexpr)                                                           \
  __shared__ __align__(16) unsigned short smem[16384]; /* 32 KB */                 \
  unsigned short* As = smem;                                                       \
  unsigned short* Bs = smem + 8192;                                                \
  int tid = threadIdx.x;                                                           \
  int w = tid >> 6, lane = tid & 63;                                               \
  int m0 = blockIdx.y * 128, n0 = blockIdx.x * 128;                                \
  int m_off = (w & 1) * 64, n_off = (w >> 1) * 64;                                 \
  floatx4 acc[4][4] = {};                                                          \
  int sr = lane >> 2, sc = (lane & 3) * 8;                                         \
  int lrow = lane & 15, kq = (lane >> 4) * 8;

#define GSTAGE(A, Wt, K, BUF, K0) { \
    _Pragma("unroll") \
    for (int s2 = 0; s2 < 2; s2++){ \
      int c = w * 2 + s2; \
      const unsigned short* ga = (A) + (size_t)(m0 + c*16 + sr) * (K) + (K0) + sc; \
      __builtin_amdgcn_global_load_lds( \
          (const __attribute__((address_space(1))) void*)ga, \
          (__attribute__((address_space(3))) void*)(As + (BUF)*4096 + c*512), 16, 0, 0); \
      const unsigned short* gb = (Wt) + (size_t)(n0 + c*16 + sr) * (K) + (K0) + sc; \
      __builtin_amdgcn_global_load_lds( \
          (const __attribute__((address_space(1))) void*)gb, \
          (__attribute__((address_space(3))) void*)(Bs + (BUF)*4096 + c*512), 16, 0, 0); \
    } }

#define GEMM_FRAGS \
    const unsigned short* Ab = As + cur*4096; \
    const unsigned short* Bb = Bs + cur*4096; \
    short8 afr[4], bfr[4]; \
    _Pragma("unroll") \
    for (int i = 0; i < 4; i++) \
      afr[i] = *(const short8*)(Ab + (m_off + i*16 + lrow)*32 + kq); \
    _Pragma("unroll") \
    for (int j = 0; j < 4; j++) \
      bfr[j] = *(const short8*)(Bb + (n_off + j*16 + lrow)*32 + kq);

// TRANSPOSED repack-to-LDS epilogue helper (f16 tile in smem, XOR-swizzled).
// acc[j][i]: n = n0+n_off+j*16+(lane>>4)*4+r ; m = m0+m_off+i*16+(lane&15).
#define REPACK_STORE(bias, R, Mv, Nv)                                              \
  __half* tileC = (__half*)smem;                                                   \
  int mlb = m_off + lrow;                                                          \
  int nlb = n_off + (kq >> 1);        /* (lane>>4)*4 */                            \
  _Pragma("unroll")                                                                \
  for (int j = 0; j < 4; j++){                                                     \
    int nl = nlb + j*16;                                                           \
    float4 b4 = make_float4(0.f,0.f,0.f,0.f);                                      \
    if (n0 + nl + 4 <= (Nv)) b4 = *(const float4*)((bias) + n0 + nl);              \
    _Pragma("unroll")                                                              \
    for (int i = 0; i < 4; i++){                                                   \
      int ml = mlb + i*16;                                                         \
      float v0 = acc[j][i][0] + b4.x;                                              \
      float v1 = acc[j][i][1] + b4.y;                                              \
      float v2 = acc[j][i][2] + b4.z;                                              \
      float v3 = acc[j][i][3] + b4.w;                                              \
      if ((R) && (m0 + ml) < (Mv)){                                                \
        uint2 rv = *(const uint2*)((R) + (size_t)(m0+ml)*(Nv) + n0 + nl);          \
        float2 r01 = __half22float2(h2_of((int)rv.x));                             \
        float2 r23 = __half22float2(h2_of((int)rv.y));                             \
        v0 += r01.x; v1 += r01.y; v2 += r23.x; v3 += r23.y;                        \
      }                                                                            \
      __half2 plo = __floats2half2_rn(v0, v1);                                     \
      __half2 phi = __floats2half2_rn(v2, v3);                                     \
      int2 pk2 = make_int2(i_of(plo), i_of(phi));                                  \
      unsigned ba = (unsigned)(ml*256 + ((nl*2) ^ ((ml & 7) << 4)));               \
      *(int2*)((char*)tileC + ba) = pk2;                                           \
    }                                                                              \
  }                                                                                \
  __syncthreads();

// f32-output GEMM, ORIGINAL orientation (16-lane f32 stores = full 64B sectors).
// C = A @ Wt^T + bias (+R f16). Used for the final out GEMM only.
__global__ __launch_bounds__(256) void k_gemm_f32(
    const unsigned short* __restrict__ A,
    const unsigned short* __restrict__ Wt,
    const float* __restrict__ bias,
    const __half* __restrict__ R,
    float* __restrict__ C,
    int M, int N, int K){
  GEMM_DECL(K)
  GSTAGE(A, Wt, K, 0, 0)
  __syncthreads();
  int cur = 0;
  for (int k0 = 0; k0 < K; k0 += 32){
    if (k0 + 32 < K){ GSTAGE(A, Wt, K, cur ^ 1, k0 + 32) }
    GEMM_FRAGS
    #pragma unroll
    for (int i = 0; i < 4; i++)
      #pragma unroll
      for (int j = 0; j < 4; j++)
        acc[i][j] = __builtin_amdgcn_mfma_f32_16x16x32_bf16(afr[i], bfr[j], acc[i][j], 0, 0, 0);
    __syncthreads();
    cur ^= 1;
  }
  int cn = n0 + n_off + lrow;
  int rbase = m0 + m_off + (kq >> 1);   // (lane>>4)*4
  #pragma unroll
  for (int j = 0; j < 4; j++){
    int n = cn + j*16;
    if (n >= N) continue;
    float bj = bias[n];
    #pragma unroll
    for (int i = 0; i < 4; i++){
      int mb = rbase + i*16;
      #pragma unroll
      for (int r = 0; r < 4; r++){
        int m = mb + r;
        if (m < M){
          float v = acc[i][j][r] + bj;
          if (R) v += __half2float(R[(size_t)m * N + n]);
          C[(size_t)m * N + n] = v;
        }
      }
    }
  }
}

// f16 row-major GEMM, TRANSPOSED mfma + LDS repack -> coalesced 16B stores.
// Fixes the 2-3x HBM write amplification of the scalar f16 epilogue
// (32B partial-sector stores caused WRITE_SIZE 119MB vs 72MB ideal in v12).
__global__ __launch_bounds__(256) void k_gemm_f16t(
    const unsigned short* __restrict__ A,
    const unsigned short* __restrict__ Wt,
    const float* __restrict__ bias,
    const __half* __restrict__ R,
    __half* __restrict__ C,
    int M, int N, int K){
  GEMM_DECL(K)
  GSTAGE(A, Wt, K, 0, 0)
  __syncthreads();
  int cur = 0;
  for (int k0 = 0; k0 < K; k0 += 32){
    if (k0 + 32 < K){ GSTAGE(A, Wt, K, cur ^ 1, k0 + 32) }
    GEMM_FRAGS
    #pragma unroll
    for (int j = 0; j < 4; j++)
      #pragma unroll
      for (int i = 0; i < 4; i++)
        acc[j][i] = __builtin_amdgcn_mfma_f32_16x16x32_bf16(bfr[j], afr[i], acc[j][i], 0, 0, 0);
    __syncthreads();
    cur ^= 1;
  }
  REPACK_STORE(bias, R, M, N)
  int tb = tid & 15, tr = tid >> 4;
  #pragma unroll
  for (int p = 0; p < 8; p++){
    int ml = p*16 + tr;
    unsigned ba = (unsigned)(ml*256 + ((tb*16) ^ ((ml & 7) << 4)));
    uint4 vv = *(const uint4*)((const char*)tileC + ba);
    int m = m0 + ml, n = n0 + tb*8;
    if (m < M && n + 8 <= N)
      *(uint4*)(C + (size_t)m * N + n) = vv;
  }
}

// Merged val+offaw GEMM. z=0: value (TRANSPOSED + repack -> f16 value layout
// [head][row][64], 128B coalesced head-rows). z=1: offaw f32 row-major
// (original orientation; f32 16-lane stores are full sectors already).
__global__ __launch_bounds__(256) void k_gemm_pair(
    const unsigned short* __restrict__ A0, const unsigned short* __restrict__ W0,
    const float* __restrict__ b0, __half* __restrict__ C0,
    const unsigned short* __restrict__ A1, const unsigned short* __restrict__ W1,
    const float* __restrict__ b1, float* __restrict__ C1,
    int M, int N, int K){
  int z = blockIdx.z;
  const unsigned short* A  = z ? A1 : A0;
  const unsigned short* Wt = z ? W1 : W0;
  GEMM_DECL(K)
  GSTAGE(A, Wt, K, 0, 0)
  __syncthreads();
  int cur = 0;
  for (int k0 = 0; k0 < K; k0 += 32){
    if (k0 + 32 < K){ GSTAGE(A, Wt, K, cur ^ 1, k0 + 32) }
    GEMM_FRAGS
    if (z == 0){
      #pragma unroll
      for (int j = 0; j < 4; j++)
        #pragma unroll
        for (int i = 0; i < 4; i++)
          acc[j][i] = __builtin_amdgcn_mfma_f32_16x16x32_bf16(bfr[j], afr[i], acc[j][i], 0, 0, 0);
    } else {
      #pragma unroll
      for (int i = 0; i < 4; i++)
        #pragma unroll
        for (int j = 0; j < 4; j++)
          acc[i][j] = __builtin_amdgcn_mfma_f32_16x16x32_bf16(afr[i], bfr[j], acc[i][j], 0, 0, 0);
    }
    __syncthreads();
    cur ^= 1;
  }
  if (z == 0){
    REPACK_STORE(b0, (const __half*)nullptr, M, N)
    int tb = tid & 15, tr = tid >> 4;
    #pragma unroll
    for (int p = 0; p < 8; p++){
      int ml = p*16 + tr;
      unsigned ba = (unsigned)(ml*256 + ((tb*16) ^ ((ml & 7) << 4)));
      uint4 vv = *(const uint4*)((const char*)tileC + ba);
      int m = m0 + ml, ng = n0 + tb*8;
      if (m < M){    // rows >= M must not spill into the next head slab
        int head = ng >> 6;
        *(uint4*)(C0 + (size_t)head * VSLAB + (size_t)m * 64 + (ng & 63)) = vv;
      }
    }
  } else {
    int cn = n0 + n_off + lrow;
    int rbase = m0 + m_off + (kq >> 1);
    #pragma unroll
    for (int j = 0; j < 4; j++){
      int n = cn + j*16;
      float bj = b1[n];
      #pragma unroll
      for (int i = 0; i < 4; i++){
        int mb = rbase + i*16;
        #pragma unroll
        for (int r = 0; r < 4; r++){
          int m = mb + r;
          if (m < M) C1[(size_t)m * N + n] = acc[i][j][r] + bj;
        }
      }
    }
  }
}

// Multi-scale deformable sampling (v8 structure -- best measured: 1-wave
// blocks, chunked XCD swizzle, f32 offaw, DPP softmax, LDS dsc table,
// permlane reduce; ~73% of the L2-gather roofline). Split into 2 launches of
// 3 heads each for rocprof top-5 visibility (perf-neutral).
__global__ __launch_bounds__(64, 4) void k_msdeform(const __half* __restrict__ vt,
                                                    const float* __restrict__ offaw,
                                                    unsigned short* __restrict__ msout,
                                                    int base){
  __shared__ __align__(16) int2 dsc[48];   // [grp][j] = {row, wgt} pairs
  int bid = blockIdx.x;
  int seq = base + (bid & 7) * ((ROWS*HEADS/2)/8) + (bid >> 3);
  int head = seq / ROWS;
  int r = seq - head * ROWS;
  int lane = threadIdx.x & 63;
  int b = (r >= NTOK) ? 1 : 0;
  int t = r - b * NTOK;

  float refd, refy, refx;
  if (t < L1START){
    int i = t;
    int dd = i / 576; int rem = i - dd*576; int yy = rem / 24; int xx = rem - yy*24;
    refd = (dd + 0.5f) * (1.f/24.f); refy = (yy + 0.5f) * (1.f/24.f); refx = (xx + 0.5f) * (1.f/24.f);
  } else if (t < L2START){
    int i = t - L1START;
    int dd = i / 144; int rem = i - dd*144; int yy = rem / 12; int xx = rem - yy*12;
    refd = (dd + 0.5f) * (1.f/12.f); refy = (yy + 0.5f) * (1.f/12.f); refx = (xx + 0.5f) * (1.f/12.f);
  } else {
    int i = t - L2START;
    int dd = i / 36; int rem = i - dd*36; int yy = rem / 6; int xx = rem - yy*6;
    refd = (dd + 0.5f) * (1.f/6.f); refy = (yy + 0.5f) * (1.f/6.f); refx = (xx + 0.5f) * (1.f/6.f);
  }

  int s   = lane & 15;     // point index (0..11 active) within group
  int grp = lane >> 4;     // (z,y) corner pair p == consumer group

  float logit = (s < 12) ? offaw[(size_t)r * 384 + 256 + head * 12 + s] : -1e30f;
  float mx = logit;
  mx = fmaxf(mx, dpp_f<ROR8>(mx));
  mx = fmaxf(mx, dpp_f<ROR4>(mx));
  mx = fmaxf(mx, dpp_f<ROR2>(mx));
  mx = fmaxf(mx, dpp_f<ROR1>(mx));
  float e = (s < 12) ? __expf(logit - mx) : 0.f;
  float sum = e;
  sum += dpp_f<ROR8>(sum);
  sum += dpp_f<ROR4>(sum);
  sum += dpp_f<ROR2>(sum);
  sum += dpp_f<ROR1>(sum);
  float aww = e / sum;     // lane p*16+j holds softmax weight of point j

  if (s < 12){
    int j = s;
    int l = j >> 2;
    int Dl  = (l == 0) ? 24 : ((l == 1) ? 12 : 6);
    int lst = (l == 0) ? 0  : ((l == 1) ? L1START : L2START);
    const float* op = offaw + (size_t)r * 384 + head * 36 + j * 3;
    float od = op[0], ox = op[1], oy = op[2];
    float fDl = (float)Dl;
    float pd = refd * fDl + od - 0.5f;
    float px = refx * fDl + ox - 0.5f;
    float py = refy * fDl + oy - 0.5f;
    float fld = floorf(pd), flx = floorf(px), fly = floorf(py);
    float fd = pd - fld, fx = px - flx, fy = py - fly;
    int d0 = (int)fld, x0 = (int)flx, y0 = (int)fly;
    int cz = grp >> 1, cy = grp & 1;
    int di = d0 + cz, yi = y0 + cy;
    bool vzy = (di >= 0) & (di < Dl) & (yi >= 0) & (yi < Dl);
    float wz = cz ? fd : 1.f - fd;
    float wy = cy ? fy : 1.f - fy;
    float wp = vzy ? (wz * aww) * wy : 0.f;
    int rs = min(max(x0, 0), Dl - 1);
    float wlo_x = (rs == x0) ? (1.f - fx) : ((rs == x0 + 1) ? fx : 0.f);
    float whi_x = ((rs == x0) && (x0 + 1 < Dl)) ? fx : 0.f;
    int dc = min(max(di, 0), Dl - 1);
    int yc = min(max(yi, 0), Dl - 1);
    int rowk = (b * NTOK + lst) + (dc * Dl + yc) * Dl + rs;    // < 32768
    __half2 wh = __floats2half2_rn(wp * wlo_x, wp * whi_x);
    dsc[grp * 12 + s] = make_int2(rowk, *(int*)&wh);
  }
  const uint4* dq = (const uint4*)dsc;
  uint4 dp0 = dq[grp*6+0], dp1 = dq[grp*6+1], dp2 = dq[grp*6+2];
  uint4 dp3 = dq[grp*6+3], dp4 = dq[grp*6+4], dp5 = dq[grp*6+5];

  const char* vbase = (const char*)(vt + (size_t)head * VSLAB);
  unsigned laneoff = (unsigned)(lane & 15) << 4;
  unsigned selperm = (lane & 8) ? 0x03020302u : 0x01000100u;

  int rw[12] = {(int)dp0.x,(int)dp0.z,(int)dp1.x,(int)dp1.z,(int)dp2.x,(int)dp2.z,
                (int)dp3.x,(int)dp3.z,(int)dp4.x,(int)dp4.z,(int)dp5.x,(int)dp5.z};
  unsigned wg[12] = {dp0.y,dp0.w,dp1.y,dp1.w,dp2.y,dp2.w,
                     dp3.y,dp3.w,dp4.y,dp4.w,dp5.y,dp5.w};

  uint4 vd[12];
  #pragma unroll
  for (int j = 0; j < 12; j++)
    vd[j] = *(const uint4*)(vbase + ((((unsigned)rw[j]) << 7) + laneoff));
  unsigned wsel[12];
  #pragma unroll
  for (int j = 0; j < 12; j++)
    wsel[j] = __builtin_amdgcn_perm(wg[j], wg[j], selperm);

  __half2 hz; *(int*)&hz = 0;
  __half2 a0 = hz, a1 = hz, a2 = hz, a3 = hz;
  #pragma unroll
  for (int j = 0; j < 12; j++){
    __half2 wh = *(__half2*)&wsel[j];
    uint4 v = vd[j];
    a0 = __hfma2(wh, *(__half2*)&v.x, a0);
    a1 = __hfma2(wh, *(__half2*)&v.y, a1);
    a2 = __hfma2(wh, *(__half2*)&v.z, a2);
    a3 = __hfma2(wh, *(__half2*)&v.w, a3);
  }

  a0 = __hadd2(a0, h2_of(dpp_i<ROR8>(i_of(a0))));
  a1 = __hadd2(a1, h2_of(dpp_i<ROR8>(i_of(a1))));
  a2 = __hadd2(a2, h2_of(dpp_i<ROR8>(i_of(a2))));
  a3 = __hadd2(a3, h2_of(dpp_i<ROR8>(i_of(a3))));
  {
    int t0 = __shfl_xor(i_of(a0), 16, 64); a0 = __hadd2(a0, h2_of(t0));
    int t1 = __shfl_xor(i_of(a1), 16, 64); a1 = __hadd2(a1, h2_of(t1));
    int t2 = __shfl_xor(i_of(a2), 16, 64); a2 = __hadd2(a2, h2_of(t2));
    int t3 = __shfl_xor(i_of(a3), 16, 64); a3 = __hadd2(a3, h2_of(t3));
  }
  a0 = xor32_hadd(a0);
  a1 = xor32_hadd(a1);
  a2 = xor32_hadd(a2);
  a3 = xor32_hadd(a3);

  if (lane < 8){
    float2 f0 = __half22float2(a0), f1 = __half22float2(a1);
    float2 f2 = __half22float2(a2), f3 = __half22float2(a3);
    uint4 pk;
    pk.x = cvt_pk_bf16(f0.x, f0.y);
    pk.y = cvt_pk_bf16(f1.x, f1.y);
    pk.z = cvt_pk_bf16(f2.x, f2.y);
    pk.w = cvt_pk_bf16(f3.x, f3.y);
    *(uint4*)(msout + (size_t)r * DIM + head * 64 + lane * 8) = pk;
  }
}

// depthwise 3x3x3 SAME conv per level segment + exact GELU; bf16 output.
__global__ void k_dwconv_gelu(const __half* __restrict__ h, const float* __restrict__ dww,
                              const float* __restrict__ dwb, unsigned short* __restrict__ h2){
  int gid = blockIdx.x * blockDim.x + threadIdx.x;
  if (gid >= ROWS * 24) return;
  int c4 = gid % 24;
  int r = gid / 24;
  int c = c4 * 4;
  int b = (r >= NTOK) ? 1 : 0;
  int t = r - b * NTOK;
  int base, DL, i;
  if (t < L1START){ base = 0; DL = 24; i = t; }
  else if (t < L2START){ base = L1START; DL = 12; i = t - L1START; }
  else { base = L2START; DL = 6; i = t - L2START; }
  int dd, yy, xx;
  if (DL == 24){ dd = i / 576; int rem = i - dd*576; yy = rem / 24; xx = rem - yy*24; }
  else if (DL == 12){ dd = i / 144; int rem = i - dd*144; yy = rem / 12; xx = rem - yy*12; }
  else { dd = i / 36; int rem = i - dd*36; yy = rem / 6; xx = rem - yy*6; }
  float4 acc = {0.f, 0.f, 0.f, 0.f};
  #pragma unroll
  for (int kz = 0; kz < 3; kz++){
    int nd = dd + kz - 1; if (nd < 0 || nd >= DL) continue;
    #pragma unroll
    for (int ky = 0; ky < 3; ky++){
      int ny = yy + ky - 1; if (ny < 0 || ny >= DL) continue;
      #pragma unroll
      for (int kx = 0; kx < 3; kx++){
        int nx = xx + kx - 1; if (nx < 0 || nx >= DL) continue;
        int nt = base + (nd * DL + ny) * DL + nx;
        uint2 raw = *(const uint2*)(h + ((size_t)(b*NTOK + nt)) * HID + c);
        float2 h01 = __half22float2(h2_of((int)raw.x));
        float2 h23 = __half22float2(h2_of((int)raw.y));
        float4 wv = *(const float4*)(dww + (size_t)((kz*3 + ky)*3 + kx) * HID + c);
        acc.x += h01.x * wv.x; acc.y += h01.y * wv.y;
        acc.z += h23.x * wv.z; acc.w += h23.y * wv.w;
      }
    }
  }
  float4 bv = *(const float4*)(dwb + c);
  acc.x += bv.x; acc.y += bv.y; acc.z += bv.z; acc.w += bv.w;
  const float k = 0.70710678118654752440f;
  float g0 = 0.5f * acc.x * (1.f + erff(acc.x * k));
  float g1 = 0.5f * acc.y * (1.f + erff(acc.y * k));
  float g2 = 0.5f * acc.z * (1.f + erff(acc.z * k));
  float g3 = 0.5f * acc.w * (1.f + erff(acc.w * k));
  uint2 pk;
  pk.x = ((unsigned)f2bf(g1) << 16) | (unsigned)f2bf(g0);
  pk.y = ((unsigned)f2bf(g3) << 16) | (unsigned)f2bf(g2);
  *(uint2*)(h2 + (size_t)r * HID + c) = pk;
}

extern "C" void kernel_launch(void* const* d_in, const int* in_sizes, int n_in,
                              void* d_out, int out_size, void* d_ws, size_t ws_size,
                              hipStream_t stream){
  const float* query = (const float*)d_in[0];
  const float* feat  = (const float*)d_in[2];
  const float* qnw = (const float*)d_in[8],  *qnb = (const float*)d_in[9];
  const float* fnw = (const float*)d_in[10], *fnb = (const float*)d_in[11];
  const float* eqw = (const float*)d_in[12], *eqb = (const float*)d_in[13];
  const float* efw = (const float*)d_in[14], *efb = (const float*)d_in[15];
  const float* ffw = (const float*)d_in[16], *ffb = (const float*)d_in[17];
  const float* off_w = (const float*)d_in[18], *off_b = (const float*)d_in[19];
  const float* aw_w  = (const float*)d_in[20], *aw_b  = (const float*)d_in[21];
  const float* val_w = (const float*)d_in[22], *val_b = (const float*)d_in[23];
  const float* out_w = (const float*)d_in[24], *out_b = (const float*)d_in[25];
  const float* fc1_w = (const float*)d_in[26], *fc1_b = (const float*)d_in[27];
  const float* dw_w  = (const float*)d_in[28], *dw_b  = (const float*)d_in[29];
  const float* fc2_w = (const float*)d_in[30], *fc2_b = (const float*)d_in[31];
  float* out = (float*)d_out;

  // workspace layout (lifetime-disjoint aliasing)
  char* p = (char*)d_ws;
  __half* qn            = (__half*)p;         p += (size_t)ROWS*384*2;  // qn f16; later h2
  unsigned short* aq    = (unsigned short*)p; p += (size_t)MPAD*384*2;  // aq -> t
  unsigned short* af    = (unsigned short*)p; p += (size_t)MPAD*384*2;  // af -> msout
  __half* value_t       = (__half*)p;         p += (size_t)HEADS*VSLAB*2; // value; later h
  float* offaw          = (float*)p;          p += (size_t)ROWS*384*4;  // off+aw f32; later y1
  unsigned short* wt_val   = (unsigned short*)p; p += (size_t)384*384*2;
  unsigned short* wt_offaw = (unsigned short*)p; p += (size_t)384*384*2;
  unsigned short* wt_out   = (unsigned short*)p; p += (size_t)384*384*2;
  unsigned short* wt_fc1   = (unsigned short*)p; p += (size_t)128*384*2;
  unsigned short* wt_fc2   = (unsigned short*)p; p += (size_t)384*96*2;
  float* offaw_b           = (float*)p;          p += (size_t)384*4;
  // aliases (lifetime-disjoint)
  unsigned short* t_buf  = aq;                    // MPAD*384 bf16
  unsigned short* msout  = af;                    // MPAD*384 bf16
  __half* y1             = (__half*)offaw;        // MPAD*384 f16 fits in ROWS*384*4
  __half* h_buf          = value_t;               // MPAD*96 f16 (value dead post-msdeform)
  unsigned short* h2_buf = (unsigned short*)qn;   // MPAD*96 bf16 (qn dead post-out-GEMM)

  k_cvt_all<<<(531840 + 255)/256, 256, 0, stream>>>(val_w, off_w, aw_w, out_w, fc1_w, fc2_w,
                                                    off_b, aw_b,
                                                    wt_val, wt_offaw, wt_out, wt_fc1, wt_fc2,
                                                    offaw_b, (unsigned short*)value_t);

  int lnBlocks = ROWS / 4;
  k_ln_front<<<lnBlocks, 256, 0, stream>>>(query, feat, qnw, qnb, fnw, fnb,
                                           eqw, eqb, efw, efb, qn, aq, af);

  dim3 gN384(3, MPAD/128), gN128(1, MPAD/128), gPair(3, MPAD/128, 2);

  // value (f16 [head][row][64], coalesced repack) + offaw (f32) in ONE launch
  k_gemm_pair<<<gPair, 256, 0, stream>>>(af, wt_val, val_b, value_t,
                                         aq, wt_offaw, offaw_b, offaw,
                                         ROWS, 384, 384);
  // deformable sampling -> msout (bf16; af dead). Two half-launches.
  k_msdeform<<<(ROWS*HEADS)/2, 64, 0, stream>>>(value_t, offaw, msout, 0);
  k_msdeform<<<(ROWS*HEADS)/2, 64, 0, stream>>>(value_t, offaw, msout, (ROWS*HEADS)/2);
  // y1(f16) = msout @ out_w + out_b + qn(f16)   (offaw dead)
  k_gemm_f16t<<<gN384, 256, 0, stream>>>(msout, wt_out, out_b, qn, y1, ROWS, 384, 384);
  // t = LN(y1, ffn_norm)  (aq dead)
  k_ln<<<lnBlocks, 256, 0, stream>>>(y1, ffw, ffb, t_buf);
  // h(f16) = t @ fc1_w + fc1_b   (value dead)
  k_gemm_f16t<<<gN128, 256, 0, stream>>>(t_buf, wt_fc1, fc1_b, nullptr, h_buf, ROWS, 96, 384);
  // h2 = gelu(dwconv(h))    (qn dead)
  k_dwconv_gelu<<<(ROWS * 24 + 255)/256, 256, 0, stream>>>(h_buf, dw_w, dw_b, h2_buf);
  // out(f32) = h2 @ fc2_w + fc2_b + y1(f16)
  k_gemm_f32<<<gN384, 256, 0, stream>>>(h2_buf, wt_fc2, fc2_b, y1, out, ROWS, 384, 96);
}